// Round 16
// baseline (168.168 us; speedup 1.0000x reference)
//
#include <hip/hip_runtime.h>
#include <stdint.h>

#define BATCH 32
#define CH    256
#define TLEN  4096
#define TN    64
#define TPAD  4100          // aT rows per batch strip: 2 pad + 4096 + 2 pad
#define SST   68            // phase-B f32 scratch row stride

typedef short    bf16x8 __attribute__((ext_vector_type(8)));
typedef float    f32x4  __attribute__((ext_vector_type(4)));
typedef uint16_t u16x4  __attribute__((ext_vector_type(4)));
typedef uint16_t u16x8  __attribute__((ext_vector_type(8)));

__device__ __attribute__((aligned(16))) uint16_t g_w1eff[CH * CH];
__device__ __attribute__((aligned(16))) float g_tap[5 * CH];   // tap-major
__device__ __attribute__((aligned(16))) float g_bias[CH];

static __device__ __forceinline__ uint16_t f32_to_bf16(float f) {
    uint32_t u = __builtin_bit_cast(uint32_t, f);
    u += 0x7FFFu + ((u >> 16) & 1u);
    return (uint16_t)(u >> 16);
}
static __device__ __forceinline__ float bf16_to_f32(uint16_t h) {
    uint32_t u = ((uint32_t)h) << 16;
    return __builtin_bit_cast(float, u);
}
// tanh-form gelu folded into exp2
static __device__ __forceinline__ float gelu_fast(float x) {
    const float A = 2.3022082f;
    const float B = 0.10294331f;
    float x2 = x * x;
    float z  = x * fmaf(x2, B, A);
    float e  = exp2f(z);
    float r  = __builtin_amdgcn_rcpf(1.0f + e);
    return fmaf(-x, r, x);
}

__global__ void prep_kernel(const float* __restrict__ w1, const float* __restrict__ b1,
                            const float* __restrict__ w3, const float* __restrict__ b3,
                            const float* __restrict__ w5, const float* __restrict__ b5,
                            const float* __restrict__ wc, const float* __restrict__ bc) {
    const int o = blockIdx.x;
    const int c = threadIdx.x;
    const float wc0 = wc[o * 3 + 0];
    g_w1eff[o * CH + c] = f32_to_bf16(wc0 * w1[o * CH + c]);
    if (c == 0) {
        const float wc1 = wc[o * 3 + 1], wc2 = wc[o * 3 + 2];
        g_tap[0 * CH + o] = wc2 * w5[o * 5 + 0];
        g_tap[1 * CH + o] = wc1 * w3[o * 3 + 0] + wc2 * w5[o * 5 + 1];
        g_tap[2 * CH + o] = wc1 * w3[o * 3 + 1] + wc2 * w5[o * 5 + 2];
        g_tap[3 * CH + o] = wc1 * w3[o * 3 + 2] + wc2 * w5[o * 5 + 3];
        g_tap[4 * CH + o] = wc2 * w5[o * 5 + 4];
        g_bias[o] = wc0 * b1[o] + wc1 * b3[o] + wc2 * b5[o] + bc[o];
    }
}

// k1: gelu + cast + transpose into aT[b][strip_row][c] bf16, where
// strip_row = 2 + t, element (t,c) stored at col c ^ ((t&7)<<3).
// sL swizzle: element (c=cr, t) lives at sL[cr*72 + ((t&7) | (((t>>3)^(cr>>3))<<3))]
// -> transpose-read gather over 8 ch-rows hits 8 distinct banks (was 8-way).
__global__ __launch_bounds__(256, 4)
void gelu_tr_kernel(const float* __restrict__ x, uint16_t* __restrict__ aT) {
    __shared__ __attribute__((aligned(16))) uint16_t sL[64 * 72];   // 9216 B

    const int tid = threadIdx.x;
    const int tb = blockIdx.x, cb = blockIdx.y, b = blockIdx.z;
    const int t0 = tb * 64, c0 = cb * 64;

    {
        const int cr = tid >> 2;       // 0..63 channel-local
        const int q  = tid & 3;        // 0..3 t-quarter (16 t)
        const float* xr = x + ((size_t)(b * CH + c0 + cr)) * TLEN + t0 + q * 16;
        f32x4 v0 = *(const f32x4*)(xr + 0);
        f32x4 v1 = *(const f32x4*)(xr + 4);
        f32x4 v2 = *(const f32x4*)(xr + 8);
        f32x4 v3 = *(const f32x4*)(xr + 12);
        u16x8 p0, p1;
#pragma unroll
        for (int j = 0; j < 4; ++j) {
            p0[j]     = f32_to_bf16(gelu_fast(v0[j]));
            p0[4 + j] = f32_to_bf16(gelu_fast(v1[j]));
            p1[j]     = f32_to_bf16(gelu_fast(v2[j]));
            p1[4 + j] = f32_to_bf16(gelu_fast(v3[j]));
        }
        const int b0 = (((q * 2 + 0) ^ (cr >> 3)) << 3);
        const int b1 = (((q * 2 + 1) ^ (cr >> 3)) << 3);
        *(u16x8*)(&sL[cr * 72 + b0]) = p0;
        *(u16x8*)(&sL[cr * 72 + b1]) = p1;
    }
    __syncthreads();

    uint16_t* aTb = aT + (size_t)b * TPAD * CH;
#pragma unroll
    for (int i = 0; i < 2; ++i) {
        const int idx = tid + i * 256;
        const int tr  = idx >> 3;      // 0..63
        const int ch  = idx & 7;       // 0..7 c-chunk
        const int t   = t0 + tr;
        const int swz = (t & 7) << 3;
        const int cin = (tr & 7) | ((((tr >> 3) ^ ch) & 7) << 3);
        u16x8 o;
#pragma unroll
        for (int j = 0; j < 8; ++j) o[j] = sL[(ch * 8 + j) * 72 + cin];
        *(u16x8*)(&aTb[(size_t)(2 + t) * CH + ((c0 + ch * 8) ^ swz)]) = o;
    }
    if (tb == 0) {
        const int pr = tid >> 6;       // 0..3
        const int cc = c0 + (tid & 63);
        const int prow = (pr < 2) ? pr : (4098 + (pr - 2));
        const int tmod = (pr < 2) ? (6 + pr) : (pr - 2);   // (t&7) of the pad row
        aTb[(size_t)prow * CH + (cc ^ (tmod << 3))] = 0;
    }
}

// k2: per (b, 64-t tile): linear 34 KB staging (nontemporal loads, all issued
// before LDS writes), pipelined K-loop (weights from L2), in-register depthwise
// fold, LDS transpose epilogue; exact f32 residual from x (cached);
// out written with NONTEMPORAL stores (bypass L3 so x+aT stay resident).
// sA row r <-> global t = t0 + r - 2; swizzle of row r = ((r+6)&7)<<3.
__global__ __launch_bounds__(256, 3)
void gemm_kernel(const uint16_t* __restrict__ aT, const float* __restrict__ x,
                 float* __restrict__ out) {
    __shared__ __attribute__((aligned(16))) uint16_t sA[68 * CH];      // 34816 B
    __shared__ __attribute__((aligned(16))) float    sS[4 * 16 * SST]; // 17408 B

    const int tid  = threadIdx.x;
    const int lane = tid & 63;
    const int wid  = tid >> 6;
    const int b    = blockIdx.y;
    const int t0   = blockIdx.x * TN;

    const float* __restrict__ xb = x + (size_t)b * CH * TLEN;
    float* __restrict__ ob = out + (size_t)b * CH * TLEN;

    // ---- staging: 2176 16B chunks; nontemporal loads issued before LDS writes ----
    {
        const u16x8* gsrc = (const u16x8*)(aT + (size_t)b * TPAD * CH + (size_t)t0 * CH);
        u16x8 stg[8], stgT;
#pragma unroll
        for (int i = 0; i < 8; ++i) stg[i] = __builtin_nontemporal_load(&gsrc[tid + i * 256]);
        const bool tail = (tid < 128);
        if (tail) stgT = __builtin_nontemporal_load(&gsrc[tid + 2048]);
        u16x8* ldst = (u16x8*)sA;
#pragma unroll
        for (int i = 0; i < 8; ++i) ldst[tid + i * 256] = stg[i];
        if (tail) ldst[tid + 2048] = stgT;
    }
    __syncthreads();   // B1

    f32x4 acc[4][4];
    const f32x4 vzero = {0.f, 0.f, 0.f, 0.f};
#pragma unroll
    for (int mi = 0; mi < 4; ++mi)
#pragma unroll
        for (int ni = 0; ni < 4; ++ni) acc[mi][ni] = vzero;

    const int m0   = wid * 64;
    const int colt = lane & 15;
    const int kgrp = (lane >> 4) * 8;

    // ---- K loop, 1-deep ping-pong; weights global (L2), a from sA ----
    const int swzB = (colt & 7) << 3;
    int rowB[4];
#pragma unroll
    for (int ni = 0; ni < 4; ++ni) rowB[ni] = (ni * 16 + colt + 2) * CH;

    bf16x8 afb[2][4], bfb[2][4];
#pragma unroll
    for (int mi = 0; mi < 4; ++mi) {
        const int co = m0 + mi * 16 + colt;
        afb[0][mi] = *(const bf16x8*)(g_w1eff + co * CH + kgrp);
    }
#pragma unroll
    for (int ni = 0; ni < 4; ++ni)
        bfb[0][ni] = *(const bf16x8*)(&sA[rowB[ni] + (kgrp ^ swzB)]);
#pragma unroll
    for (int s = 0; s < 8; ++s) {
        const int cur = s & 1, nxt = cur ^ 1;
        if (s < 7) {
            const int kk = (s + 1) * 32;
#pragma unroll
            for (int mi = 0; mi < 4; ++mi) {
                const int co = m0 + mi * 16 + colt;
                afb[nxt][mi] = *(const bf16x8*)(g_w1eff + co * CH + kk + kgrp);
            }
            const int cin = kk + kgrp;
#pragma unroll
            for (int ni = 0; ni < 4; ++ni)
                bfb[nxt][ni] = *(const bf16x8*)(&sA[rowB[ni] + (cin ^ swzB)]);
        }
#pragma unroll
        for (int mi = 0; mi < 4; ++mi)
#pragma unroll
            for (int ni = 0; ni < 4; ++ni)
                acc[mi][ni] = __builtin_amdgcn_mfma_f32_16x16x32_bf16(afb[cur][mi], bfb[cur][ni], acc[mi][ni], 0, 0, 0);
    }

    // ---- phase A: depthwise + bias folded into acc ----
    const int rg = (lane >> 4) * 4;
    int swzA[5];
#pragma unroll
    for (int k = 0; k < 5; ++k) swzA[k] = ((colt + k + 6) & 7) << 3;
#pragma unroll
    for (int mi = 0; mi < 4; ++mi) {
        const int c = m0 + mi * 16 + rg;
        const f32x4 tp0 = *(const f32x4*)(g_tap + 0 * CH + c);
        const f32x4 tp1 = *(const f32x4*)(g_tap + 1 * CH + c);
        const f32x4 tp2 = *(const f32x4*)(g_tap + 2 * CH + c);
        const f32x4 tp3 = *(const f32x4*)(g_tap + 3 * CH + c);
        const f32x4 tp4 = *(const f32x4*)(g_tap + 4 * CH + c);
        const f32x4 bsv = *(const f32x4*)(g_bias + c);
#pragma unroll
        for (int ni = 0; ni < 4; ++ni) {
            const int t = ni * 16 + colt;
            u16x4 a0 = *(const u16x4*)(&sA[(t + 0) * CH + (c ^ swzA[0])]);
            u16x4 a1 = *(const u16x4*)(&sA[(t + 1) * CH + (c ^ swzA[1])]);
            u16x4 a2 = *(const u16x4*)(&sA[(t + 2) * CH + (c ^ swzA[2])]);
            u16x4 a3 = *(const u16x4*)(&sA[(t + 3) * CH + (c ^ swzA[3])]);
            u16x4 a4 = *(const u16x4*)(&sA[(t + 4) * CH + (c ^ swzA[4])]);
#pragma unroll
            for (int r = 0; r < 4; ++r) {
                float d = tp0[r] * bf16_to_f32(a0[r]);
                d = fmaf(tp1[r], bf16_to_f32(a1[r]), d);
                d = fmaf(tp2[r], bf16_to_f32(a2[r]), d);
                d = fmaf(tp3[r], bf16_to_f32(a3[r]), d);
                d = fmaf(tp4[r], bf16_to_f32(a4[r]), d);
                acc[mi][ni][r] += d + bsv[r];
            }
        }
    }

    // ---- phase B: wave-private transpose; exact f32 residual; NT out stores ----
    float* __restrict__ sw = sS + wid * (16 * SST);
    const int ci = lane >> 2;          // 0..15 channel-local
    const int q  = lane & 3;           // 0..3 -> 16 t each

#pragma unroll
    for (int mi = 0; mi < 4; ++mi) {
        const int cc = m0 + mi * 16 + ci;
        const float* xrow = xb + (size_t)cc * TLEN + t0 + q * 16;
        f32x4 xv0 = *(const f32x4*)(xrow + 0);
        f32x4 xv1 = *(const f32x4*)(xrow + 4);
        f32x4 xv2 = *(const f32x4*)(xrow + 8);
        f32x4 xv3 = *(const f32x4*)(xrow + 12);
#pragma unroll
        for (int ni = 0; ni < 4; ++ni) {
            const int t = ni * 16 + colt;
#pragma unroll
            for (int r = 0; r < 4; ++r) sw[(rg + r) * SST + t] = acc[mi][ni][r];
        }
        float* orow = ob + (size_t)cc * TLEN + t0 + q * 16;
        const float* srow = sw + ci * SST + q * 16;
        f32x4 s0 = *(const f32x4*)(srow + 0);
        f32x4 s1 = *(const f32x4*)(srow + 4);
        f32x4 s2 = *(const f32x4*)(srow + 8);
        f32x4 s3 = *(const f32x4*)(srow + 12);
        __builtin_nontemporal_store(s0 + xv0, (f32x4*)(orow + 0));
        __builtin_nontemporal_store(s1 + xv1, (f32x4*)(orow + 4));
        __builtin_nontemporal_store(s2 + xv2, (f32x4*)(orow + 8));
        __builtin_nontemporal_store(s3 + xv3, (f32x4*)(orow + 12));
    }
}

extern "C" void kernel_launch(void* const* d_in, const int* in_sizes, int n_in,
                              void* d_out, int out_size, void* d_ws, size_t ws_size,
                              hipStream_t stream) {
    const float* x  = (const float*)d_in[0];
    const float* w1 = (const float*)d_in[1];
    const float* b1 = (const float*)d_in[2];
    const float* w3 = (const float*)d_in[3];
    const float* b3 = (const float*)d_in[4];
    const float* w5 = (const float*)d_in[5];
    const float* b5 = (const float*)d_in[6];
    const float* wc = (const float*)d_in[7];
    const float* bc = (const float*)d_in[8];
    float* out = (float*)d_out;
    uint16_t* aT = (uint16_t*)d_ws;    // 32*4100*256*2 B = 67.2 MB

    prep_kernel<<<dim3(CH), dim3(CH), 0, stream>>>(w1, b1, w3, b3, w5, b5, wc, bc);
    gelu_tr_kernel<<<dim3(TLEN / 64, CH / 64, BATCH), dim3(256), 0, stream>>>(x, aT);
    gemm_kernel<<<dim3(TLEN / TN, BATCH), dim3(256), 0, stream>>>(aT, x, out);
}

// Round 17
// 118.241 us; speedup vs baseline: 1.4223x; 1.4223x over previous
//
#include <hip/hip_runtime.h>
#include <stdint.h>

#define BATCH 32
#define CH    256
#define TLEN  4096
#define TN    64
#define TPAD  4100          // aT rows per batch strip: 2 pad + 4096 + 2 pad
#define SST   68            // phase-B f32 scratch row stride

typedef short    bf16x8 __attribute__((ext_vector_type(8)));
typedef float    f32x4  __attribute__((ext_vector_type(4)));
typedef uint16_t u16x4  __attribute__((ext_vector_type(4)));
typedef uint16_t u16x8  __attribute__((ext_vector_type(8)));

// packed fragment-order weights: g_wpk[(s*CH + co)*32 + g*8 + e] = w1eff[co][32s+8g+e]
// -> the 64 lanes of a wave-load (co = m0+mi*16+colt, kgrp = g*8) read ONE
//    contiguous 1KB block instead of a 16-line gather.
__device__ __attribute__((aligned(16))) uint16_t g_wpk[CH * CH];
__device__ __attribute__((aligned(16))) float g_tap[5 * CH];   // tap-major
__device__ __attribute__((aligned(16))) float g_bias[CH];

static __device__ __forceinline__ uint16_t f32_to_bf16(float f) {
    uint32_t u = __builtin_bit_cast(uint32_t, f);
    u += 0x7FFFu + ((u >> 16) & 1u);
    return (uint16_t)(u >> 16);
}
static __device__ __forceinline__ float bf16_to_f32(uint16_t h) {
    uint32_t u = ((uint32_t)h) << 16;
    return __builtin_bit_cast(float, u);
}
// tanh-form gelu folded into exp2
static __device__ __forceinline__ float gelu_fast(float x) {
    const float A = 2.3022082f;
    const float B = 0.10294331f;
    float x2 = x * x;
    float z  = x * fmaf(x2, B, A);
    float e  = exp2f(z);
    float r  = __builtin_amdgcn_rcpf(1.0f + e);
    return fmaf(-x, r, x);
}

__global__ void prep_kernel(const float* __restrict__ w1, const float* __restrict__ b1,
                            const float* __restrict__ w3, const float* __restrict__ b3,
                            const float* __restrict__ w5, const float* __restrict__ b5,
                            const float* __restrict__ wc, const float* __restrict__ bc) {
    const int o = blockIdx.x;
    const int c = threadIdx.x;
    const float wc0 = wc[o * 3 + 0];
    const int s = c >> 5, g = (c >> 3) & 3, e = c & 7;
    g_wpk[(s * CH + o) * 32 + g * 8 + e] = f32_to_bf16(wc0 * w1[o * CH + c]);
    if (c == 0) {
        const float wc1 = wc[o * 3 + 1], wc2 = wc[o * 3 + 2];
        g_tap[0 * CH + o] = wc2 * w5[o * 5 + 0];
        g_tap[1 * CH + o] = wc1 * w3[o * 3 + 0] + wc2 * w5[o * 5 + 1];
        g_tap[2 * CH + o] = wc1 * w3[o * 3 + 1] + wc2 * w5[o * 5 + 2];
        g_tap[3 * CH + o] = wc1 * w3[o * 3 + 2] + wc2 * w5[o * 5 + 3];
        g_tap[4 * CH + o] = wc2 * w5[o * 5 + 4];
        g_bias[o] = wc0 * b1[o] + wc1 * b3[o] + wc2 * b5[o] + bc[o];
    }
}

// k1: gelu + cast + transpose into aT[b][strip_row][c] bf16, where
// strip_row = 2 + t, element (t,c) stored at col c ^ ((t&7)<<3).
// sL swizzle: element (c=cr, t) lives at sL[cr*72 + ((t&7) | (((t>>3)^(cr>>3))<<3))]
// -> transpose-read gather over 8 ch-rows hits 8 distinct banks (was 8-way).
__global__ __launch_bounds__(256, 4)
void gelu_tr_kernel(const float* __restrict__ x, uint16_t* __restrict__ aT) {
    __shared__ __attribute__((aligned(16))) uint16_t sL[64 * 72];   // 9216 B

    const int tid = threadIdx.x;
    const int tb = blockIdx.x, cb = blockIdx.y, b = blockIdx.z;
    const int t0 = tb * 64, c0 = cb * 64;

    {
        const int cr = tid >> 2;       // 0..63 channel-local
        const int q  = tid & 3;        // 0..3 t-quarter (16 t)
        const float* xr = x + ((size_t)(b * CH + c0 + cr)) * TLEN + t0 + q * 16;
        f32x4 v0 = *(const f32x4*)(xr + 0);
        f32x4 v1 = *(const f32x4*)(xr + 4);
        f32x4 v2 = *(const f32x4*)(xr + 8);
        f32x4 v3 = *(const f32x4*)(xr + 12);
        u16x8 p0, p1;
#pragma unroll
        for (int j = 0; j < 4; ++j) {
            p0[j]     = f32_to_bf16(gelu_fast(v0[j]));
            p0[4 + j] = f32_to_bf16(gelu_fast(v1[j]));
            p1[j]     = f32_to_bf16(gelu_fast(v2[j]));
            p1[4 + j] = f32_to_bf16(gelu_fast(v3[j]));
        }
        const int b0 = (((q * 2 + 0) ^ (cr >> 3)) << 3);
        const int b1 = (((q * 2 + 1) ^ (cr >> 3)) << 3);
        *(u16x8*)(&sL[cr * 72 + b0]) = p0;
        *(u16x8*)(&sL[cr * 72 + b1]) = p1;
    }
    __syncthreads();

    uint16_t* aTb = aT + (size_t)b * TPAD * CH;
#pragma unroll
    for (int i = 0; i < 2; ++i) {
        const int idx = tid + i * 256;
        const int tr  = idx >> 3;      // 0..63
        const int ch  = idx & 7;       // 0..7 c-chunk
        const int t   = t0 + tr;
        const int swz = (t & 7) << 3;
        const int cin = (tr & 7) | ((((tr >> 3) ^ ch) & 7) << 3);
        u16x8 o;
#pragma unroll
        for (int j = 0; j < 8; ++j) o[j] = sL[(ch * 8 + j) * 72 + cin];
        *(u16x8*)(&aTb[(size_t)(2 + t) * CH + ((c0 + ch * 8) ^ swz)]) = o;
    }
    if (tb == 0) {
        const int pr = tid >> 6;       // 0..3
        const int cc = c0 + (tid & 63);
        const int prow = (pr < 2) ? pr : (4098 + (pr - 2));
        const int tmod = (pr < 2) ? (6 + pr) : (pr - 2);   // (t&7) of the pad row
        aTb[(size_t)prow * CH + (cc ^ (tmod << 3))] = 0;
    }
}

// k2 (r13 structure): per (b, 64-t tile): linear 34 KB staging (loads issued
// before LDS writes), pipelined K-loop with PACKED coalesced weight loads,
// in-register depthwise fold, LDS transpose epilogue, exact f32 residual.
// sA row r <-> global t = t0 + r - 2; swizzle of row r = ((r+6)&7)<<3.
__global__ __launch_bounds__(256, 3)
void gemm_kernel(const uint16_t* __restrict__ aT, const float* __restrict__ x,
                 float* __restrict__ out) {
    __shared__ __attribute__((aligned(16))) uint16_t sA[68 * CH];      // 34816 B
    __shared__ __attribute__((aligned(16))) float    sS[4 * 16 * SST]; // 17408 B

    const int tid  = threadIdx.x;
    const int lane = tid & 63;
    const int wid  = tid >> 6;
    const int b    = blockIdx.y;
    const int t0   = blockIdx.x * TN;

    const float* __restrict__ xb = x + (size_t)b * CH * TLEN;
    float* __restrict__ ob = out + (size_t)b * CH * TLEN;

    // ---- staging: 2176 16B chunks; all loads issued before any LDS write ----
    {
        const u16x8* gsrc = (const u16x8*)(aT + (size_t)b * TPAD * CH + (size_t)t0 * CH);
        u16x8 stg[8], stgT;
#pragma unroll
        for (int i = 0; i < 8; ++i) stg[i] = gsrc[tid + i * 256];
        const bool tail = (tid < 128);
        if (tail) stgT = gsrc[tid + 2048];
        u16x8* ldst = (u16x8*)sA;
#pragma unroll
        for (int i = 0; i < 8; ++i) ldst[tid + i * 256] = stg[i];
        if (tail) ldst[tid + 2048] = stgT;
    }
    __syncthreads();   // B1

    f32x4 acc[4][4];
    const f32x4 vzero = {0.f, 0.f, 0.f, 0.f};
#pragma unroll
    for (int mi = 0; mi < 4; ++mi)
#pragma unroll
        for (int ni = 0; ni < 4; ++ni) acc[mi][ni] = vzero;

    const int m0   = wid * 64;
    const int colt = lane & 15;
    const int kgrp = (lane >> 4) * 8;

    // ---- K loop, 1-deep ping-pong; packed weights (contiguous 1KB/wave-load) ----
    const int swzB = (colt & 7) << 3;
    int rowB[4];
#pragma unroll
    for (int ni = 0; ni < 4; ++ni) rowB[ni] = (ni * 16 + colt + 2) * CH;

    bf16x8 afb[2][4], bfb[2][4];
#pragma unroll
    for (int mi = 0; mi < 4; ++mi) {
        const int co = m0 + mi * 16 + colt;
        afb[0][mi] = *(const bf16x8*)(g_wpk + co * 32 + kgrp);
    }
#pragma unroll
    for (int ni = 0; ni < 4; ++ni)
        bfb[0][ni] = *(const bf16x8*)(&sA[rowB[ni] + (kgrp ^ swzB)]);
#pragma unroll
    for (int s = 0; s < 8; ++s) {
        const int cur = s & 1, nxt = cur ^ 1;
        if (s < 7) {
            const int sbase = (s + 1) * CH * 32;
#pragma unroll
            for (int mi = 0; mi < 4; ++mi) {
                const int co = m0 + mi * 16 + colt;
                afb[nxt][mi] = *(const bf16x8*)(g_wpk + sbase + co * 32 + kgrp);
            }
            const int cin = (s + 1) * 32 + kgrp;
#pragma unroll
            for (int ni = 0; ni < 4; ++ni)
                bfb[nxt][ni] = *(const bf16x8*)(&sA[rowB[ni] + (cin ^ swzB)]);
        }
#pragma unroll
        for (int mi = 0; mi < 4; ++mi)
#pragma unroll
            for (int ni = 0; ni < 4; ++ni)
                acc[mi][ni] = __builtin_amdgcn_mfma_f32_16x16x32_bf16(afb[cur][mi], bfb[cur][ni], acc[mi][ni], 0, 0, 0);
    }

    // ---- phase A: depthwise + bias folded into acc ----
    const int rg = (lane >> 4) * 4;
    int swzA[5];
#pragma unroll
    for (int k = 0; k < 5; ++k) swzA[k] = ((colt + k + 6) & 7) << 3;
#pragma unroll
    for (int mi = 0; mi < 4; ++mi) {
        const int c = m0 + mi * 16 + rg;
        const f32x4 tp0 = *(const f32x4*)(g_tap + 0 * CH + c);
        const f32x4 tp1 = *(const f32x4*)(g_tap + 1 * CH + c);
        const f32x4 tp2 = *(const f32x4*)(g_tap + 2 * CH + c);
        const f32x4 tp3 = *(const f32x4*)(g_tap + 3 * CH + c);
        const f32x4 tp4 = *(const f32x4*)(g_tap + 4 * CH + c);
        const f32x4 bsv = *(const f32x4*)(g_bias + c);
#pragma unroll
        for (int ni = 0; ni < 4; ++ni) {
            const int t = ni * 16 + colt;
            u16x4 a0 = *(const u16x4*)(&sA[(t + 0) * CH + (c ^ swzA[0])]);
            u16x4 a1 = *(const u16x4*)(&sA[(t + 1) * CH + (c ^ swzA[1])]);
            u16x4 a2 = *(const u16x4*)(&sA[(t + 2) * CH + (c ^ swzA[2])]);
            u16x4 a3 = *(const u16x4*)(&sA[(t + 3) * CH + (c ^ swzA[3])]);
            u16x4 a4 = *(const u16x4*)(&sA[(t + 4) * CH + (c ^ swzA[4])]);
#pragma unroll
            for (int r = 0; r < 4; ++r) {
                float d = tp0[r] * bf16_to_f32(a0[r]);
                d = fmaf(tp1[r], bf16_to_f32(a1[r]), d);
                d = fmaf(tp2[r], bf16_to_f32(a2[r]), d);
                d = fmaf(tp3[r], bf16_to_f32(a3[r]), d);
                d = fmaf(tp4[r], bf16_to_f32(a4[r]), d);
                acc[mi][ni][r] += d + bsv[r];
            }
        }
    }

    // ---- phase B: wave-private transpose; exact f32 residual from x ----
    float* __restrict__ sw = sS + wid * (16 * SST);
    const int ci = lane >> 2;          // 0..15 channel-local
    const int q  = lane & 3;           // 0..3 -> 16 t each

#pragma unroll
    for (int mi = 0; mi < 4; ++mi) {
        const int cc = m0 + mi * 16 + ci;
        const float* xrow = xb + (size_t)cc * TLEN + t0 + q * 16;
        f32x4 xv0 = *(const f32x4*)(xrow + 0);
        f32x4 xv1 = *(const f32x4*)(xrow + 4);
        f32x4 xv2 = *(const f32x4*)(xrow + 8);
        f32x4 xv3 = *(const f32x4*)(xrow + 12);
#pragma unroll
        for (int ni = 0; ni < 4; ++ni) {
            const int t = ni * 16 + colt;
#pragma unroll
            for (int r = 0; r < 4; ++r) sw[(rg + r) * SST + t] = acc[mi][ni][r];
        }
        float* orow = ob + (size_t)cc * TLEN + t0 + q * 16;
        const float* srow = sw + ci * SST + q * 16;
        f32x4 s0 = *(const f32x4*)(srow + 0);
        f32x4 s1 = *(const f32x4*)(srow + 4);
        f32x4 s2 = *(const f32x4*)(srow + 8);
        f32x4 s3 = *(const f32x4*)(srow + 12);
        *(f32x4*)(orow + 0)  = s0 + xv0;
        *(f32x4*)(orow + 4)  = s1 + xv1;
        *(f32x4*)(orow + 8)  = s2 + xv2;
        *(f32x4*)(orow + 12) = s3 + xv3;
    }
}

extern "C" void kernel_launch(void* const* d_in, const int* in_sizes, int n_in,
                              void* d_out, int out_size, void* d_ws, size_t ws_size,
                              hipStream_t stream) {
    const float* x  = (const float*)d_in[0];
    const float* w1 = (const float*)d_in[1];
    const float* b1 = (const float*)d_in[2];
    const float* w3 = (const float*)d_in[3];
    const float* b3 = (const float*)d_in[4];
    const float* w5 = (const float*)d_in[5];
    const float* b5 = (const float*)d_in[6];
    const float* wc = (const float*)d_in[7];
    const float* bc = (const float*)d_in[8];
    float* out = (float*)d_out;
    uint16_t* aT = (uint16_t*)d_ws;    // 32*4100*256*2 B = 67.2 MB

    prep_kernel<<<dim3(CH), dim3(CH), 0, stream>>>(w1, b1, w3, b3, w5, b5, wc, bc);
    gelu_tr_kernel<<<dim3(TLEN / 64, CH / 64, BATCH), dim3(256), 0, stream>>>(x, aT);
    gemm_kernel<<<dim3(TLEN / TN, BATCH), dim3(256), 0, stream>>>(aT, x, out);
}